// Round 1
// baseline (32266.745 us; speedup 1.0000x reference)
//
#include <hip/hip_runtime.h>
#include <hip/hip_bf16.h>

#define T_STEPS 2048
#define BATCH   64
#define HID     512
#define NBG 2      // batch groups (32 rows each)
#define NCG 16     // column-chunk groups (32 cols each)
#define CHUNK 32

typedef unsigned short u16;
typedef __attribute__((ext_vector_type(4))) float f32x4;
typedef __attribute__((ext_vector_type(8))) short bf16x8;

static __device__ __forceinline__ u16 f2bf(float f) {
  union { float f; unsigned u; } v; v.f = f;
  unsigned u = v.u;
  return (u16)((u + 0x7fffu + ((u >> 16) & 1u)) >> 16);
}
static __device__ __forceinline__ float bf2f(u16 h) {
  union { unsigned u; float f; } v; v.u = ((unsigned)h) << 16; return v.f;
}

// ---------------- weight fp32 -> bf16 ----------------
__global__ __launch_bounds__(256) void cvt_weights(
    const float* __restrict__ wxf, const float* __restrict__ wxh,
    const float* __restrict__ whf, const float* __restrict__ whh,
    u16* __restrict__ o_wxf, u16* __restrict__ o_wxh,
    u16* __restrict__ o_whf, u16* __restrict__ o_whh) {
  int i = blockIdx.x * 256 + threadIdx.x;   // grid covers 512*512 exactly
  o_wxf[i] = f2bf(wxf[i]);
  o_wxh[i] = f2bf(wxh[i]);
  o_whf[i] = f2bf(whf[i]);
  o_whh[i] = f2bf(whh[i]);
}

// ---------------- xf/xh = x @ Wx^T + b  (bf16 out) ----------------
// C[M=131072, N=1024]; cols 0..511 -> xf (Wx_f, b_f), 512..1023 -> xh
__global__ __launch_bounds__(256) void proj_gemm(
    const float* __restrict__ x,
    const u16* __restrict__ wxf, const u16* __restrict__ wxh,
    const float* __restrict__ b_f, const float* __restrict__ b_h,
    u16* __restrict__ xfo, u16* __restrict__ xho) {
  const int bid = blockIdx.x;
  const int mbase = (bid >> 4) * 64;
  const int nbase = (bid & 15) * 64;
  const int tid = threadIdx.x;
  const int lane = tid & 63, wv = tid >> 6;
  const int l15 = lane & 15, lhi = lane >> 4;
  __shared__ u16 a_lds[64 * 48];   // stride 48 (96B): 16B-aligned rows, uniform banks

  // B-fragment base pointers: n fixed per (lane, ntile)
  const u16* bptr[4];
#pragma unroll
  for (int ntt = 0; ntt < 4; ++ntt) {
    int n = nbase + ntt * 16 + l15;
    bptr[ntt] = (n < 512) ? (wxf + (size_t)n * 512) : (wxh + (size_t)(n - 512) * 512);
  }
  const int arow = tid >> 2;
  const int akq = (tid & 3) * 8;
  const float* asrc = x + (size_t)(mbase + arow) * 512 + akq;

  f32x4 acc[4];
#pragma unroll
  for (int i = 0; i < 4; ++i) acc[i] = (f32x4){0.f, 0.f, 0.f, 0.f};

  for (int kk = 0; kk < 512; kk += 32) {
    float4 v0 = *(const float4*)(asrc + kk);
    float4 v1 = *(const float4*)(asrc + kk + 4);
    u16* dst = &a_lds[arow * 48 + akq];
    dst[0] = f2bf(v0.x); dst[1] = f2bf(v0.y); dst[2] = f2bf(v0.z); dst[3] = f2bf(v0.w);
    dst[4] = f2bf(v1.x); dst[5] = f2bf(v1.y); dst[6] = f2bf(v1.z); dst[7] = f2bf(v1.w);
    __syncthreads();
    bf16x8 a = *(const bf16x8*)&a_lds[(wv * 16 + l15) * 48 + lhi * 8];
#pragma unroll
    for (int ntt = 0; ntt < 4; ++ntt) {
      bf16x8 b = *(const bf16x8*)(bptr[ntt] + kk + lhi * 8);
      acc[ntt] = __builtin_amdgcn_mfma_f32_16x16x32_bf16(a, b, acc[ntt], 0, 0, 0);
    }
    __syncthreads();
  }
#pragma unroll
  for (int ntt = 0; ntt < 4; ++ntt) {
    int n = nbase + ntt * 16 + l15;
    float bias = (n < 512) ? b_f[n] : b_h[n - 512];
    u16* op = (n < 512) ? (xfo + n) : (xho + (n - 512));
#pragma unroll
    for (int q = 0; q < 4; ++q) {
      int row = mbase + wv * 16 + lhi * 4 + q;
      op[(size_t)row * 512] = f2bf(acc[ntt][q] + bias);
    }
  }
}

// ---------------- persistent recurrent scan ----------------
// 32 WGs: bg in {0,1} owns rows bg*32..+31; cg in 0..15 owns cols cg*32..+31.
// Per step: stage1 f/g for own cols (needs full h of own rows -> exchange),
//           stage2 candidate + blend (needs full g -> exchange).
// Flags are monotonic step counters; 0xAA poison is negative => "not ready".
__global__ __launch_bounds__(256) void mgu_scan(
    const float* __restrict__ h0,
    const u16* __restrict__ whf, const u16* __restrict__ whh,
    const u16* __restrict__ xf, const u16* __restrict__ xh,
    int* hflags, int* gflags, u16* hexch, u16* gexch,
    float* __restrict__ y, float* __restrict__ hfin) {
  const int bg = blockIdx.x / NCG;
  const int cg = blockIdx.x % NCG;
  const int tid = threadIdx.x;
  const int lane = tid & 63;
  const int wv = tid >> 6;
  const int l15 = lane & 15, lhi = lane >> 4;
  const int mt = wv & 1, nt = wv >> 1;   // 2x2 16x16 tiles, one per wave

  __shared__ u16 w_lds[2 * 2 * 16 * 64 * 8];  // 64 KB: [which][nt][kb][lane][8] B-frags
  __shared__ u16 h_lds[32 * 512];             // 32 KB: A operand, 16B-group rotated

  // one-time: pack this WG's weight column slices as B-fragments
  for (int s = tid; s < 4096; s += 256) {
    int ln = s & 63;
    int kb = (s >> 6) & 15;
    int wnt = (s >> 10) & 1;
    int which = s >> 11;
    int n = cg * CHUNK + wnt * 16 + (ln & 15);
    int k = kb * 32 + (ln >> 4) * 8;
    const u16* src = (which ? whh : whf) + (size_t)n * 512 + k;
    *(bf16x8*)&w_lds[(((which * 2 + wnt) * 16 + kb) * 64 + ln) * 8] = *(const bf16x8*)src;
  }

  const int rowbase = bg * 32;
  const int r_a = mt * 16 + l15;           // A-frag local row
  const int cloc = nt * 16 + l15;
  const int gcol = cg * CHUNK + cloc;      // global output column
  const int myflag = (bg * NCG + cg) * 16; // 64B-strided flag slot

  for (int t = 0; t < T_STEPS; ++t) {
    // ---- stage h into LDS (A operand, rotated groups) ----
    if (t == 0) {
      for (int s = tid; s < 2048; s += 256) {
        int r = s >> 6, g8 = s & 63;
        int slot = (g8 + r) & 63;
        const float* src = h0 + (size_t)(rowbase + r) * 512 + g8 * 8;
        u16* dst = &h_lds[r * 512 + slot * 8];
#pragma unroll
        for (int j = 0; j < 8; ++j) dst[j] = f2bf(src[j]);
      }
    } else {
      if (tid < NCG) {
        const int fidx = (bg * NCG + tid) * 16;
        while (__hip_atomic_load(&hflags[fidx], __ATOMIC_ACQUIRE,
                                 __HIP_MEMORY_SCOPE_AGENT) < t) {}
      }
      __syncthreads();
      const u16* src0 = hexch + ((t - 1) & 3) * (BATCH * 512) + rowbase * 512;
      for (int s = tid; s < 2048; s += 256) {
        int r = s >> 6, g8 = s & 63;
        int slot = (g8 + r) & 63;
        *(bf16x8*)&h_lds[r * 512 + slot * 8] = *(const bf16x8*)(src0 + r * 512 + g8 * 8);
      }
    }
    __syncthreads();

    // ---- GEMM 1: P = h @ Wh_f_chunk^T ----
    f32x4 acc = {0.f, 0.f, 0.f, 0.f};
#pragma unroll
    for (int kb = 0; kb < 16; ++kb) {
      int slot = (kb * 4 + lhi + r_a) & 63;
      bf16x8 a = *(const bf16x8*)&h_lds[r_a * 512 + slot * 8];
      bf16x8 b = *(const bf16x8*)&w_lds[((nt * 16 + kb) * 64 + lane) * 8];
      acc = __builtin_amdgcn_mfma_f32_16x16x32_bf16(a, b, acc, 0, 0, 0);
    }

    float fv[4], hv[4];
    const u16* xfp = xf + ((size_t)t * BATCH + rowbase) * 512 + gcol;
#pragma unroll
    for (int q = 0; q < 4; ++q) {
      int r = mt * 16 + lhi * 4 + q;
      float pre = acc[q] + bf2f(xfp[(size_t)r * 512]);
      float f = 1.f / (1.f + __expf(-pre));
      int slot = ((gcol >> 3) + r) & 63;
      float h = bf2f(h_lds[r * 512 + slot * 8 + (gcol & 7)]);
      fv[q] = f; hv[q] = h;
    }
    u16* gdst = gexch + (t & 3) * (BATCH * 512) + rowbase * 512 + gcol;
#pragma unroll
    for (int q = 0; q < 4; ++q) {
      int r = mt * 16 + lhi * 4 + q;
      gdst[r * 512] = f2bf(fv[q] * hv[q]);
    }
    __threadfence();
    __syncthreads();
    if (tid == 0)
      __hip_atomic_store(&gflags[myflag], t + 1, __ATOMIC_RELEASE, __HIP_MEMORY_SCOPE_AGENT);

    // ---- stage g into LDS ----
    if (tid < NCG) {
      const int fidx = (bg * NCG + tid) * 16;
      while (__hip_atomic_load(&gflags[fidx], __ATOMIC_ACQUIRE,
                               __HIP_MEMORY_SCOPE_AGENT) < t + 1) {}
    }
    __syncthreads();
    {
      const u16* src0 = gexch + (t & 3) * (BATCH * 512) + rowbase * 512;
      for (int s = tid; s < 2048; s += 256) {
        int r = s >> 6, g8 = s & 63;
        int slot = (g8 + r) & 63;
        *(bf16x8*)&h_lds[r * 512 + slot * 8] = *(const bf16x8*)(src0 + r * 512 + g8 * 8);
      }
    }
    __syncthreads();

    // ---- GEMM 2: Q = g @ Wh_h_chunk^T ----
    f32x4 acc2 = {0.f, 0.f, 0.f, 0.f};
#pragma unroll
    for (int kb = 0; kb < 16; ++kb) {
      int slot = (kb * 4 + lhi + r_a) & 63;
      bf16x8 a = *(const bf16x8*)&h_lds[r_a * 512 + slot * 8];
      bf16x8 b = *(const bf16x8*)&w_lds[(((2 + nt) * 16 + kb) * 64 + lane) * 8];
      acc2 = __builtin_amdgcn_mfma_f32_16x16x32_bf16(a, b, acc2, 0, 0, 0);
    }
    const u16* xhp = xh + ((size_t)t * BATCH + rowbase) * 512 + gcol;
    float* yp = y + ((size_t)t * BATCH + rowbase) * 512 + gcol;
    u16* hdst = hexch + (t & 3) * (BATCH * 512) + rowbase * 512 + gcol;
#pragma unroll
    for (int q = 0; q < 4; ++q) {
      int r = mt * 16 + lhi * 4 + q;
      float pre = acc2[q] + bf2f(xhp[(size_t)r * 512]);
      float e = __expf(-2.f * fabsf(pre));           // overflow-safe tanh
      float ht = copysignf((1.f - e) / (1.f + e), pre);
      float hn = (1.f - fv[q]) * hv[q] + fv[q] * ht;
      yp[(size_t)r * 512] = hn;
      hdst[r * 512] = f2bf(hn);
      if (t == T_STEPS - 1) hfin[(rowbase + r) * 512 + gcol] = hn;
    }
    __threadfence();
    __syncthreads();
    if (tid == 0)
      __hip_atomic_store(&hflags[myflag], t + 1, __ATOMIC_RELEASE, __HIP_MEMORY_SCOPE_AGENT);
  }
}

extern "C" void kernel_launch(void* const* d_in, const int* in_sizes, int n_in,
                              void* d_out, int out_size, void* d_ws, size_t ws_size,
                              hipStream_t stream) {
  const float* x   = (const float*)d_in[0];
  const float* h0  = (const float*)d_in[1];
  const float* Wxf = (const float*)d_in[2];
  const float* Whf = (const float*)d_in[3];
  const float* bf_ = (const float*)d_in[4];
  const float* Wxh = (const float*)d_in[5];
  const float* Whh = (const float*)d_in[6];
  const float* bh_ = (const float*)d_in[7];
  float* y = (float*)d_out;
  float* hfin = y + (size_t)T_STEPS * BATCH * HID;

  char* ws = (char*)d_ws;
  u16* wxf_b = (u16*)(ws + 0);
  u16* wxh_b = (u16*)(ws + 524288);
  u16* whf_b = (u16*)(ws + 1048576);
  u16* whh_b = (u16*)(ws + 1572864);
  int* hflags = (int*)(ws + 2097152);             // 32 flags * 64 B
  int* gflags = (int*)(ws + 2099200);
  u16* hexch  = (u16*)(ws + 2101248);             // 4*64*512 bf16 ring
  u16* gexch  = (u16*)(ws + 2363392);
  u16* xfw    = (u16*)(ws + 2625536);             // [T*B, 512] bf16
  u16* xhw    = (u16*)(ws + 2625536 + 134217728);
  // total ws use: ~271 MB

  hipLaunchKernelGGL(cvt_weights, dim3(1024), dim3(256), 0, stream,
                     Wxf, Wxh, Whf, Whh, wxf_b, wxh_b, whf_b, whh_b);
  hipLaunchKernelGGL(proj_gemm, dim3(32768), dim3(256), 0, stream,
                     x, wxf_b, wxh_b, bf_, bh_, xfw, xhw);
  hipLaunchKernelGGL(mgu_scan, dim3(NBG * NCG), dim3(256), 0, stream,
                     h0, whf_b, whh_b, xfw, xhw, hflags, gflags, hexch, gexch, y, hfin);
}

// Round 2
// 24098.622 us; speedup vs baseline: 1.3389x; 1.3389x over previous
//
#include <hip/hip_runtime.h>
#include <hip/hip_bf16.h>

#define T_STEPS 2048
#define BATCH   64
#define HID     512
#define NBG 2      // batch groups (32 rows each)
#define NCG 16     // column-chunk groups (32 cols each)
#define CHUNK 32

typedef unsigned short u16;
typedef unsigned int u32;
typedef unsigned long long u64;
typedef __attribute__((ext_vector_type(4))) float f32x4;
typedef __attribute__((ext_vector_type(8))) short bf16x8;

static __device__ __forceinline__ u16 f2bf(float f) {
  union { float f; unsigned u; } v; v.f = f;
  unsigned u = v.u;
  return (u16)((u + 0x7fffu + ((u >> 16) & 1u)) >> 16);
}
static __device__ __forceinline__ float bf2f(u16 h) {
  union { unsigned u; float f; } v; v.u = ((unsigned)h) << 16; return v.f;
}

// relaxed agent-scope accessors: per-instruction coherence (bypass L1/L2),
// NO buffer_inv / buffer_wbl2 cache maintenance (that was the round-1 15us/step).
static __device__ __forceinline__ void st_rlx32(u32* p, u32 v) {
  __hip_atomic_store(p, v, __ATOMIC_RELAXED, __HIP_MEMORY_SCOPE_AGENT);
}
static __device__ __forceinline__ u64 ld_rlx64(const u64* p) {
  return __hip_atomic_load(p, __ATOMIC_RELAXED, __HIP_MEMORY_SCOPE_AGENT);
}
static __device__ __forceinline__ int ld_rlx_i(const int* p) {
  return __hip_atomic_load(p, __ATOMIC_RELAXED, __HIP_MEMORY_SCOPE_AGENT);
}
static __device__ __forceinline__ void st_rlx_i(int* p, int v) {
  __hip_atomic_store(p, v, __ATOMIC_RELAXED, __HIP_MEMORY_SCOPE_AGENT);
}

// ---------------- weight fp32 -> bf16 ----------------
__global__ __launch_bounds__(256) void cvt_weights(
    const float* __restrict__ wxf, const float* __restrict__ wxh,
    const float* __restrict__ whf, const float* __restrict__ whh,
    u16* __restrict__ o_wxf, u16* __restrict__ o_wxh,
    u16* __restrict__ o_whf, u16* __restrict__ o_whh) {
  int i = blockIdx.x * 256 + threadIdx.x;   // grid covers 512*512 exactly
  o_wxf[i] = f2bf(wxf[i]);
  o_wxh[i] = f2bf(wxh[i]);
  o_whf[i] = f2bf(whf[i]);
  o_whh[i] = f2bf(whh[i]);
}

// ---------------- xf/xh = x @ Wx^T + b  (bf16 out) ----------------
__global__ __launch_bounds__(256) void proj_gemm(
    const float* __restrict__ x,
    const u16* __restrict__ wxf, const u16* __restrict__ wxh,
    const float* __restrict__ b_f, const float* __restrict__ b_h,
    u16* __restrict__ xfo, u16* __restrict__ xho) {
  const int bid = blockIdx.x;
  const int mbase = (bid >> 4) * 64;
  const int nbase = (bid & 15) * 64;
  const int tid = threadIdx.x;
  const int lane = tid & 63, wv = tid >> 6;
  const int l15 = lane & 15, lhi = lane >> 4;
  __shared__ u16 a_lds[64 * 48];

  const u16* bptr[4];
#pragma unroll
  for (int ntt = 0; ntt < 4; ++ntt) {
    int n = nbase + ntt * 16 + l15;
    bptr[ntt] = (n < 512) ? (wxf + (size_t)n * 512) : (wxh + (size_t)(n - 512) * 512);
  }
  const int arow = tid >> 2;
  const int akq = (tid & 3) * 8;
  const float* asrc = x + (size_t)(mbase + arow) * 512 + akq;

  f32x4 acc[4];
#pragma unroll
  for (int i = 0; i < 4; ++i) acc[i] = (f32x4){0.f, 0.f, 0.f, 0.f};

  for (int kk = 0; kk < 512; kk += 32) {
    float4 v0 = *(const float4*)(asrc + kk);
    float4 v1 = *(const float4*)(asrc + kk + 4);
    u16* dst = &a_lds[arow * 48 + akq];
    dst[0] = f2bf(v0.x); dst[1] = f2bf(v0.y); dst[2] = f2bf(v0.z); dst[3] = f2bf(v0.w);
    dst[4] = f2bf(v1.x); dst[5] = f2bf(v1.y); dst[6] = f2bf(v1.z); dst[7] = f2bf(v1.w);
    __syncthreads();
    bf16x8 a = *(const bf16x8*)&a_lds[(wv * 16 + l15) * 48 + lhi * 8];
#pragma unroll
    for (int ntt = 0; ntt < 4; ++ntt) {
      bf16x8 b = *(const bf16x8*)(bptr[ntt] + kk + lhi * 8);
      acc[ntt] = __builtin_amdgcn_mfma_f32_16x16x32_bf16(a, b, acc[ntt], 0, 0, 0);
    }
    __syncthreads();
  }
#pragma unroll
  for (int ntt = 0; ntt < 4; ++ntt) {
    int n = nbase + ntt * 16 + l15;
    float bias = (n < 512) ? b_f[n] : b_h[n - 512];
    u16* op = (n < 512) ? (xfo + n) : (xho + (n - 512));
#pragma unroll
    for (int q = 0; q < 4; ++q) {
      int row = mbase + wv * 16 + lhi * 4 + q;
      op[(size_t)row * 512] = f2bf(acc[ntt][q] + bias);
    }
  }
}

// ---------------- persistent recurrent scan ----------------
__global__ __launch_bounds__(256) void mgu_scan(
    const float* __restrict__ h0,
    const u16* __restrict__ whf, const u16* __restrict__ whh,
    const u16* __restrict__ xf, const u16* __restrict__ xh,
    int* hflags, int* gflags, u16* hexch, u16* gexch,
    float* __restrict__ y, float* __restrict__ hfin) {
  const int bg = blockIdx.x / NCG;
  const int cg = blockIdx.x % NCG;
  const int tid = threadIdx.x;
  const int lane = tid & 63;
  const int wv = tid >> 6;
  const int l15 = lane & 15, lhi = lane >> 4;
  const int mt = wv & 1, nt = wv >> 1;

  __shared__ u16 w_lds[2 * 2 * 16 * 64 * 8];  // 64 KB B-frags
  __shared__ u16 h_lds[32 * 512];             // 32 KB A operand, rotated groups

  for (int s = tid; s < 4096; s += 256) {
    int ln = s & 63;
    int kb = (s >> 6) & 15;
    int wnt = (s >> 10) & 1;
    int which = s >> 11;
    int n = cg * CHUNK + wnt * 16 + (ln & 15);
    int k = kb * 32 + (ln >> 4) * 8;
    const u16* src = (which ? whh : whf) + (size_t)n * 512 + k;
    *(bf16x8*)&w_lds[(((which * 2 + wnt) * 16 + kb) * 64 + ln) * 8] = *(const bf16x8*)src;
  }

  const int rowbase = bg * 32;
  const int r_a = mt * 16 + l15;
  const int cloc = nt * 16 + l15;
  const int gcol = cg * CHUNK + cloc;
  const int myflag = (bg * NCG + cg) * 16;

  for (int t = 0; t < T_STEPS; ++t) {
    // ---- stage h into LDS ----
    if (t == 0) {
      for (int s = tid; s < 2048; s += 256) {
        int r = s >> 6, g8 = s & 63;
        int slot = (g8 + r) & 63;
        const float* src = h0 + (size_t)(rowbase + r) * 512 + g8 * 8;
        u16* dst = &h_lds[r * 512 + slot * 8];
#pragma unroll
        for (int j = 0; j < 8; ++j) dst[j] = f2bf(src[j]);
      }
    } else {
      if (tid < NCG) {
        const int fidx = (bg * NCG + tid) * 16;
        while (ld_rlx_i(&hflags[fidx]) < t) {}
      }
      __syncthreads();
      const u16* src0 = hexch + ((t - 1) & 3) * (BATCH * 512) + rowbase * 512;
      for (int s = tid; s < 2048; s += 256) {
        int r = s >> 6, g8 = s & 63;
        int slot = (g8 + r) & 63;
        const u64* p = (const u64*)(src0 + r * 512 + g8 * 8);
        u64 lo = ld_rlx64(p);
        u64 hi = ld_rlx64(p + 1);
        u64* d = (u64*)&h_lds[r * 512 + slot * 8];
        d[0] = lo; d[1] = hi;
      }
    }
    __syncthreads();

    // ---- GEMM 1: P = h @ Wh_f_chunk^T ----
    f32x4 acc = {0.f, 0.f, 0.f, 0.f};
#pragma unroll
    for (int kb = 0; kb < 16; ++kb) {
      int slot = (kb * 4 + lhi + r_a) & 63;
      bf16x8 a = *(const bf16x8*)&h_lds[r_a * 512 + slot * 8];
      bf16x8 b = *(const bf16x8*)&w_lds[((nt * 16 + kb) * 64 + lane) * 8];
      acc = __builtin_amdgcn_mfma_f32_16x16x32_bf16(a, b, acc, 0, 0, 0);
    }

    float fv[4], hv[4];
    const u16* xfp = xf + ((size_t)t * BATCH + rowbase) * 512 + gcol;
#pragma unroll
    for (int q = 0; q < 4; ++q) {
      int r = mt * 16 + lhi * 4 + q;
      float pre = acc[q] + bf2f(xfp[(size_t)r * 512]);
      float f = 1.f / (1.f + __expf(-pre));
      int slot = ((gcol >> 3) + r) & 63;
      float h = bf2f(h_lds[r * 512 + slot * 8 + (gcol & 7)]);
      fv[q] = f; hv[q] = h;
    }
    // write g = f*h, packed 2 cols/dword via lane-pair shuffle, relaxed stores
    {
      u32* gx32 = (u32*)(gexch + (t & 3) * (BATCH * 512) + rowbase * 512);
#pragma unroll
      for (int q = 0; q < 4; ++q) {
        float g = fv[q] * hv[q];
        float og = __shfl_xor(g, 1);
        if (!(l15 & 1)) {
          int r = mt * 16 + lhi * 4 + q;
          u32 w = (u32)f2bf(g) | ((u32)f2bf(og) << 16);
          st_rlx32(gx32 + r * 256 + (gcol >> 1), w);
        }
      }
    }
    asm volatile("s_waitcnt vmcnt(0)" ::: "memory");
    __syncthreads();
    if (tid == 0) st_rlx_i(&gflags[myflag], t + 1);

    // ---- stage g into LDS ----
    if (tid < NCG) {
      const int fidx = (bg * NCG + tid) * 16;
      while (ld_rlx_i(&gflags[fidx]) < t + 1) {}
    }
    __syncthreads();
    {
      const u16* src0 = gexch + (t & 3) * (BATCH * 512) + rowbase * 512;
      for (int s = tid; s < 2048; s += 256) {
        int r = s >> 6, g8 = s & 63;
        int slot = (g8 + r) & 63;
        const u64* p = (const u64*)(src0 + r * 512 + g8 * 8);
        u64 lo = ld_rlx64(p);
        u64 hi = ld_rlx64(p + 1);
        u64* d = (u64*)&h_lds[r * 512 + slot * 8];
        d[0] = lo; d[1] = hi;
      }
    }
    __syncthreads();

    // ---- GEMM 2: Q = g @ Wh_h_chunk^T ----
    f32x4 acc2 = {0.f, 0.f, 0.f, 0.f};
#pragma unroll
    for (int kb = 0; kb < 16; ++kb) {
      int slot = (kb * 4 + lhi + r_a) & 63;
      bf16x8 a = *(const bf16x8*)&h_lds[r_a * 512 + slot * 8];
      bf16x8 b = *(const bf16x8*)&w_lds[(((2 + nt) * 16 + kb) * 64 + lane) * 8];
      acc2 = __builtin_amdgcn_mfma_f32_16x16x32_bf16(a, b, acc2, 0, 0, 0);
    }
    const u16* xhp = xh + ((size_t)t * BATCH + rowbase) * 512 + gcol;
    float* yp = y + ((size_t)t * BATCH + rowbase) * 512 + gcol;
    u32* hx32 = (u32*)(hexch + (t & 3) * (BATCH * 512) + rowbase * 512);
    float hnv[4];
#pragma unroll
    for (int q = 0; q < 4; ++q) {
      int r = mt * 16 + lhi * 4 + q;
      float pre = acc2[q] + bf2f(xhp[(size_t)r * 512]);
      float e = __expf(-2.f * fabsf(pre));
      float ht = copysignf((1.f - e) / (1.f + e), pre);
      float hn = (1.f - fv[q]) * hv[q] + fv[q] * ht;
      hnv[q] = hn;
      yp[(size_t)r * 512] = hn;
      if (t == T_STEPS - 1) hfin[(rowbase + r) * 512 + gcol] = hn;
    }
#pragma unroll
    for (int q = 0; q < 4; ++q) {
      float hn = hnv[q];
      float oh = __shfl_xor(hn, 1);
      if (!(l15 & 1)) {
        int r = mt * 16 + lhi * 4 + q;
        u32 w = (u32)f2bf(hn) | ((u32)f2bf(oh) << 16);
        st_rlx32(hx32 + r * 256 + (gcol >> 1), w);
      }
    }
    asm volatile("s_waitcnt vmcnt(0)" ::: "memory");
    __syncthreads();
    if (tid == 0) st_rlx_i(&hflags[myflag], t + 1);
  }
}

extern "C" void kernel_launch(void* const* d_in, const int* in_sizes, int n_in,
                              void* d_out, int out_size, void* d_ws, size_t ws_size,
                              hipStream_t stream) {
  const float* x   = (const float*)d_in[0];
  const float* h0  = (const float*)d_in[1];
  const float* Wxf = (const float*)d_in[2];
  const float* Whf = (const float*)d_in[3];
  const float* bf_ = (const float*)d_in[4];
  const float* Wxh = (const float*)d_in[5];
  const float* Whh = (const float*)d_in[6];
  const float* bh_ = (const float*)d_in[7];
  float* y = (float*)d_out;
  float* hfin = y + (size_t)T_STEPS * BATCH * HID;

  char* ws = (char*)d_ws;
  u16* wxf_b = (u16*)(ws + 0);
  u16* wxh_b = (u16*)(ws + 524288);
  u16* whf_b = (u16*)(ws + 1048576);
  u16* whh_b = (u16*)(ws + 1572864);
  int* hflags = (int*)(ws + 2097152);
  int* gflags = (int*)(ws + 2099200);
  u16* hexch  = (u16*)(ws + 2101248);
  u16* gexch  = (u16*)(ws + 2363392);
  u16* xfw    = (u16*)(ws + 2625536);
  u16* xhw    = (u16*)(ws + 2625536 + 134217728);

  hipLaunchKernelGGL(cvt_weights, dim3(1024), dim3(256), 0, stream,
                     Wxf, Wxh, Whf, Whh, wxf_b, wxh_b, whf_b, whh_b);
  hipLaunchKernelGGL(proj_gemm, dim3(32768), dim3(256), 0, stream,
                     x, wxf_b, wxh_b, bf_, bh_, xfw, xhw);
  hipLaunchKernelGGL(mgu_scan, dim3(NBG * NCG), dim3(256), 0, stream,
                     h0, whf_b, whh_b, xfw, xhw, hflags, gflags, hexch, gexch, y, hfin);
}